// Round 10
// baseline (1417.627 us; speedup 1.0000x reference)
//
#include <hip/hip_runtime.h>

#define HH 32
#define LOG2E 1.44269504088896340736f
#define KCH 16   // TF pipeline chunk length

typedef float v2f __attribute__((ext_vector_type(2)));

// DPP: quad_perm broadcasts (gate q = lane&3) and row rotates (16-lane rows)
#define DPPF(v, ctrl) \
    __int_as_float(__builtin_amdgcn_update_dpp(0, __float_as_int(v), (ctrl), 0xF, 0xF, true))
#define QP_B0 0x00
#define QP_B1 0x55
#define QP_B2 0xAA
#define QP_B3 0xFF
#define DPP_ROR4  0x124
#define DPP_ROR8  0x128
#define SWZ(v, pat) __int_as_float(__builtin_amdgcn_ds_swizzle(__float_as_int(v), (pat)))

__device__ __forceinline__ float hw_exp2(float x) {
    float r; asm("v_exp_f32 %0, %1" : "=v"(r) : "v"(x)); return r;
}
__device__ __forceinline__ float sigm_e(float z, float e) {
    return __builtin_amdgcn_rcpf(1.0f + hw_exp2(z * e));
}
__device__ __forceinline__ v2f pk_fma(v2f a, v2f b, v2f c) {
    return __builtin_elementwise_fma(a, b, c);   // v_pk_fma_f32
}
// LDS-only barrier: drain lgkmcnt, then builtin s_barrier (no vmcnt drain;
// global stores stay in flight). Verified passing in r9.
__device__ __forceinline__ void wave_barrier() {
    asm volatile("s_waitcnt lgkmcnt(0)" ::: "memory");
    __builtin_amdgcn_s_barrier();
}
__device__ __forceinline__ void load_bc(const float* p, v2f* d) {
#pragma unroll
    for (int r = 0; r < 8; ++r) {                // 8x ds_read_b128 broadcast
        float4 v = ((const float4*)p)[r];
        d[2*r]   = (v2f){v.x, v.y};
        d[2*r+1] = (v2f){v.z, v.w};
    }
}
// TF output path: full cross-lane sum
__device__ __forceinline__ float out_reduce(float p) {
    p += DPPF(p, DPP_ROR4);
    p += DPPF(p, DPP_ROR8);
    p += SWZ(p, 0x401F);             // xor16
    p += __shfl_xor(p, 32, 64);
    return p;
}
__device__ __forceinline__ float rl(float v, int lane) {
    return __int_as_float(__builtin_amdgcn_readlane(__float_as_int(v), lane));
}
// AR feedback: register-only reduce (r6-verified). p quad-uniform per lane.
__device__ __forceinline__ float xo_reduce(float p) {
    p += DPPF(p, DPP_ROR4);
    p += DPPF(p, DPP_ROR8);          // lane = sum of its row's 4 ch
    float a0 = rl(p, 0), a1 = rl(p, 16), a2 = rl(p, 32), a3 = rl(p, 48);
    return (a0 + a1) + (a2 + a3);
}

// 2-row (A,B) dot over 16 v2f weight regs
template<bool ACC>
__device__ __forceinline__ void dot2(const v2f* hv, const v2f* mA, const v2f* mB,
                                     v2f& P0, v2f& P1, v2f& P2, v2f& P3) {
    if (ACC) {
        P0 = pk_fma(hv[0], mA[0], P0); P1 = pk_fma(hv[1], mA[1], P1);
        P2 = pk_fma(hv[0], mB[0], P2); P3 = pk_fma(hv[1], mB[1], P3);
    } else {
        P0 = hv[0] * mA[0]; P1 = hv[1] * mA[1];
        P2 = hv[0] * mB[0]; P3 = hv[1] * mB[1];
    }
#pragma unroll
    for (int r = 2; r < 16; r += 2) {
        P0 = pk_fma(hv[r],   mA[r],   P0);
        P1 = pk_fma(hv[r+1], mA[r+1], P1);
        P2 = pk_fma(hv[r],   mB[r],   P2);
        P3 = pk_fma(hv[r+1], mB[r+1], P3);
    }
}

__device__ __forceinline__ void gate_hc(float zA, float zB, float es, float mm, float cc,
                                        float& cA, float& cB, float& hA, float& hB) {
    float acA = fmaf(mm, sigm_e(zA, es), cc);
    float acB = fmaf(mm, sigm_e(zB, es), cc);
    float iA = DPPF(acA, QP_B0), fA = DPPF(acA, QP_B1);
    float gA = DPPF(acA, QP_B2), oA = DPPF(acA, QP_B3);
    float iB = DPPF(acB, QP_B0), fB = DPPF(acB, QP_B1);
    float gB = DPPF(acB, QP_B2), oB = DPPF(acB, QP_B3);
    cA = fmaf(fA, cA, iA * gA);
    cB = fmaf(fB, cB, iB * gB);
    hA = oA * fmaf(2.0f, sigm_e(cA, -2.0f * LOG2E), -1.0f);
    hB = oB * fmaf(2.0f, sigm_e(cB, -2.0f * LOG2E), -1.0f);
}

// 4 waves/block, 1 elem/block, __launch_bounds__(256,4) -> 4 waves/SIMD, <=128 reg/wave.
// Lane layout: q=lane&3 (gate), ch=lane>>2; rows (q<<5)|ch, (q<<5)|(ch+16).
// TF (3-stage chunk pipeline, barrier per chunk):
//   w0: cell1 recurrence (Whh1)   -> h1ring
//   w1: Wih2·h1 dot stage          -> zring (pre-reduced row scalars)
//   w2: cell2 gate + Whh2 carry + output
//   w3: idle (holds Whh1 for AR)
// AR (2 barriers/step, gates-vs-dots split):
//   half A: w0 alone: gate2(t-1) -> h2s; xo via register butterfly; gate1(t) -> h1x
//   half B: w1: Wih2·h1(t)->zx1; w2: Whh2·h2(t-1)->zx2; w3: Whh1·h1(t)->zx0
__global__ __launch_bounds__(256, 4)
void lstm_seq_kernel(const float* __restrict__ input,
                     const float* __restrict__ W_ih1, const float* __restrict__ W_hh1,
                     const float* __restrict__ b_ih1, const float* __restrict__ b_hh1,
                     const float* __restrict__ W_ih2, const float* __restrict__ W_hh2,
                     const float* __restrict__ b_ih2, const float* __restrict__ b_hh2,
                     const float* __restrict__ W_lin, const float* __restrict__ b_lin,
                     float* __restrict__ out, int T, int total)
{
    const int b    = blockIdx.x;
    const int tid  = threadIdx.x;
    const int wv   = tid >> 6;       // 0..3
    const int lane = tid & 63;
    const int q    = lane & 3;
    const int ch   = lane >> 2;      // 0..15
    const int rowA = (q << 5) | ch;
    const int rowB = (q << 5) | (ch + 16);
    const int zidx = (q << 4) | ch;  // 2 lanes/bank -> conflict-free scalar exchange

    __shared__ __align__(16) float h1ring[2][KCH][HH];   // w0 self + w0->w1
    __shared__ __align__(16) float zring[2][KCH][128];   // w1->w2
    __shared__ __align__(16) float h1x[HH];              // AR h1 exchange
    __shared__ __align__(16) float h2s[HH];              // h2 broadcast (TF w2 self / AR)
    __shared__ __align__(16) float zx0[128];             // Whh1·h1 row scalars
    __shared__ __align__(16) float zx1[128];             // Wih2·h1
    __shared__ __align__(16) float zx2[128];             // Whh2·h2
    __shared__ __align__(16) float c2x[HH];              // c2 handoff w2->w0

    const bool  isg = (q == 2);
    const float es  = isg ? (-2.0f * LOG2E) : (-LOG2E);
    const float mm  = isg ? 2.0f : 1.0f;
    const float cc  = isg ? -1.0f : 0.0f;

    // one matrix per wave: w0,w3 -> Whh1; w1 -> Wih2; w2 -> Whh2
    v2f mA[16], mB[16];
    {
        const float* Wsel = (wv == 1) ? W_ih2 : (wv == 2) ? W_hh2 : W_hh1;
        const v2f* pA = (const v2f*)(Wsel + rowA * HH);
        const v2f* pB = (const v2f*)(Wsel + rowB * HH);
#pragma unroll
        for (int r = 0; r < 16; ++r) { mA[r] = pA[r]; mB[r] = pB[r]; }
    }
    const float wxA = W_ih1[rowA], wxB = W_ih1[rowB];
    const float b1A = b_ih1[rowA] + b_hh1[rowA];
    const float b1B = b_ih1[rowB] + b_hh1[rowB];
    const float b2A = b_ih2[rowA] + b_hh2[rowA];
    const float b2B = b_ih2[rowB] + b_hh2[rowB];
    const float wlA = W_lin[ch], wlB = W_lin[ch + 16];
    const float blin = b_lin[0];

    float cA = 0.f, cB = 0.f;        // c1 (w0) / c2 (w2)
    v2f p0 = {0.f,0.f}, p1 = {0.f,0.f}, p2 = {0.f,0.f}, p3 = {0.f,0.f};

    const float* __restrict__ inp  = input + (size_t)b * T;
    float* __restrict__       outp = out   + (size_t)b * total;

    // ================= TF: 3-stage chunk pipeline, barrier per interval ==========
    const int NCH = (T + KCH - 1) / KCH;     // 63 chunks (0..62)
    float xcur = (wv == 0) ? inp[0] : 0.f;
    for (int k = 0; k <= NCH + 1; ++k) {     // 65 intervals, uniform barrier count
        if (wv == 0) {
            if (k < NCH) {                   // produce chunk k
                const int t0 = k * KCH;
                int S = T - t0; if (S > KCH) S = KCH;
                float* ring = &h1ring[k & 1][0][0];
                for (int s = 0; s < S; ++s) {
                    const int t = t0 + s;
                    float x = xcur;
                    int tn = t + 1;
                    xcur = inp[tn < T ? tn : 0];          // prefetch, off-path
                    v2f tA = p0 + p1, tB = p2 + p3;
                    float z1A = fmaf(x, wxA, b1A + tA.x + tA.y);
                    float z1B = fmaf(x, wxB, b1B + tB.x + tB.y);
                    float hA, hB;
                    gate_hc(z1A, z1B, es, mm, cc, cA, cB, hA, hB);
                    float* slot = ring + s * HH;
                    if (q == 0) {
                        slot[ch] = hA; slot[ch + 16] = hB;
                        if (t == T - 1) { h1x[ch] = hA; h1x[ch + 16] = hB; }
                    }
                    v2f hv[16]; load_bc(slot, hv);        // same-wave round trip
                    dot2<false>(hv, mA, mB, p0, p1, p2, p3);  // Whh1·h1(t) carry
                }
            }
        } else if (wv == 1) {
            if (k >= 1 && k <= NCH) {        // consume chunk k-1 -> zring
                const int c = k - 1, t0 = c * KCH;
                int S = T - t0; if (S > KCH) S = KCH;
                const float* ring = &h1ring[c & 1][0][0];
                float* zb = &zring[c & 1][0][0];
                for (int s = 0; s < S; ++s) {
                    v2f hv[16]; load_bc(ring + s * HH, hv);
                    v2f s0, s1, s2, s3;
                    dot2<false>(hv, mA, mB, s0, s1, s2, s3);  // Wih2·h1
                    v2f uA = s0 + s1, uB = s2 + s3;
                    float* zs = zb + s * 128;
                    zs[zidx]      = uA.x + uA.y;
                    zs[zidx + 64] = uB.x + uB.y;
                }
            }
        } else if (wv == 2) {
            if (k >= 2) {                    // consume zring chunk k-2
                const int c = k - 2, t0 = c * KCH;
                int S = T - t0; if (S > KCH) S = KCH;
                const float* zb = &zring[c & 1][0][0];
                for (int s = 0; s < S; ++s) {
                    const int t = t0 + s;
                    const float* zs = zb + s * 128;
                    float ziA = zs[zidx], ziB = zs[zidx + 64];
                    v2f tA = p0 + p1, tB = p2 + p3;
                    float z2A = b2A + ziA + tA.x + tA.y;
                    float z2B = b2B + ziB + tB.x + tB.y;
                    float hA, hB;
                    gate_hc(z2A, z2B, es, mm, cc, cA, cB, hA, hB);
                    if (q == 0) { h2s[ch] = hA; h2s[ch + 16] = hB; }
                    v2f gv[16]; load_bc(h2s, gv);         // same-wave round trip
                    dot2<false>(gv, mA, mB, p0, p1, p2, p3);  // Whh2·h2(t) carry
                    float pr = fmaf(hA, wlA, hB * wlB);
                    float ov = out_reduce(pr) + blin;
                    if (lane == 0) outp[t] = ov;
                }
                if (k == NCH + 1 && q == 0) { c2x[ch] = cA; c2x[ch + 16] = cB; }
            }
        }
        wave_barrier();
    }

    // ================= AR: 4-wave, 2 barriers/step =================
    // Entering: w0 has c1(T-1), p=Whh1·h1(T-1); h2s=h2(T-1); h1x=h1(T-1); c2x=c2(T-1).
    v2f wl[16];
    float h2a = 0.f, h2b = 0.f, d2A = 0.f, d2B = 0.f;
    if (wv == 0) {
        const v2f* wp = (const v2f*)W_lin;
#pragma unroll
        for (int r = 0; r < 16; ++r) wl[r] = wp[r];
        h2a = h2s[ch]; h2b = h2s[ch + 16];       // h2(T-1) per-lane (ordered by k-loop barrier)
        d2A = c2x[ch]; d2B = c2x[ch + 16];       // c2(T-1)
    }

    for (int t = T; t < total; ++t) {
        if (wv == 0) {
            // ---- gate2(t-1) (skipped at t==T: TF already produced h2(T-1)) ----
            if (t > T) {
                float z2A = b2A + zx1[zidx]      + zx2[zidx];
                float z2B = b2B + zx1[zidx + 64] + zx2[zidx + 64];
                float hA, hB;
                gate_hc(z2A, z2B, es, mm, cc, d2A, d2B, hA, hB);
                h2a = hA; h2b = hB;
                if (q == 0) { h2s[ch] = h2a; h2s[ch + 16] = h2b; }
            }
            // ---- feedback xo = Wlin·h2(t-1)+b : register-only butterfly ----
            float pr = fmaf(h2a, wlA, h2b * wlB);
            float xo = xo_reduce(pr) + blin;             // = out(t-1)
            if (t > T && lane == 0) outp[t - 1] = xo;    // off-chain (no vmcnt drain)
            // ---- gate1(t) ----
            float zx0A, zx0B;
            if (t == T) { v2f tA = p0 + p1, tB = p2 + p3; zx0A = tA.x + tA.y; zx0B = tB.x + tB.y; }
            else        { zx0A = zx0[zidx]; zx0B = zx0[zidx + 64]; }
            float z1A = fmaf(xo, wxA, b1A + zx0A);
            float z1B = fmaf(xo, wxB, b1B + zx0B);
            float hA, hB;
            gate_hc(z1A, z1B, es, mm, cc, cA, cB, hA, hB);
            if (q == 0) { h1x[ch] = hA; h1x[ch + 16] = hB; }
        }
        wave_barrier();                  // B1: h1x(t), h2s(t-1) visible; zx WAR safe
        if (wv == 1) {
            v2f hv[16]; load_bc(h1x, hv);
            v2f s0, s1, s2, s3;
            dot2<false>(hv, mA, mB, s0, s1, s2, s3);     // Wih2·h1(t)
            v2f uA = s0 + s1, uB = s2 + s3;
            zx1[zidx] = uA.x + uA.y; zx1[zidx + 64] = uB.x + uB.y;
        } else if (wv == 3) {
            v2f hv[16]; load_bc(h1x, hv);
            v2f s0, s1, s2, s3;
            dot2<false>(hv, mA, mB, s0, s1, s2, s3);     // Whh1·h1(t)
            v2f uA = s0 + s1, uB = s2 + s3;
            zx0[zidx] = uA.x + uA.y; zx0[zidx + 64] = uB.x + uB.y;
        } else if (wv == 2) {
            v2f gv[16]; load_bc(h2s, gv);
            v2f s0, s1, s2, s3;
            dot2<false>(gv, mA, mB, s0, s1, s2, s3);     // Whh2·h2(t-1)
            v2f uA = s0 + s1, uB = s2 + s3;
            zx2[zidx] = uA.x + uA.y; zx2[zidx + 64] = uB.x + uB.y;
        }
        wave_barrier();                  // B2: zx* visible for next step
    }
    // tail: gate2(total-1) -> out(total-1)
    if (wv == 0) {
        float z2A = b2A + zx1[zidx]      + zx2[zidx];
        float z2B = b2B + zx1[zidx + 64] + zx2[zidx + 64];
        float hA, hB;
        gate_hc(z2A, z2B, es, mm, cc, d2A, d2B, hA, hB);
        float pr = fmaf(hA, wlA, hB * wlB);
        float ov = xo_reduce(pr) + blin;
        if (lane == 0) outp[total - 1] = ov;
    }
}

extern "C" void kernel_launch(void* const* d_in, const int* in_sizes, int n_in,
                              void* d_out, int out_size, void* d_ws, size_t ws_size,
                              hipStream_t stream) {
    const int B = 1024;                 // fixed by the source module
    const int T = in_sizes[0] / B;      // 999
    const int total = out_size / B;     // T + future = 1999

    lstm_seq_kernel<<<dim3(B), dim3(256), 0, stream>>>(
        (const float*)d_in[0],
        (const float*)d_in[1], (const float*)d_in[2],
        (const float*)d_in[3], (const float*)d_in[4],
        (const float*)d_in[5], (const float*)d_in[6],
        (const float*)d_in[7], (const float*)d_in[8],
        (const float*)d_in[9], (const float*)d_in[10],
        (float*)d_out, T, total);
}

// Round 11
// 1173.301 us; speedup vs baseline: 1.2082x; 1.2082x over previous
//
#include <hip/hip_runtime.h>

#define HH 32
#define LOG2E 1.44269504088896340736f
#define KCH 32   // TF pipeline chunk length (steps per ring half); 32 halves barrier count vs 16

typedef float v2f __attribute__((ext_vector_type(2)));

// DPP: quad_perm broadcasts (gate q = lane&3) and row rotates (16-lane rows)
#define DPPF(v, ctrl) \
    __int_as_float(__builtin_amdgcn_update_dpp(0, __float_as_int(v), (ctrl), 0xF, 0xF, true))
#define QP_B0 0x00   // [0,0,0,0] -> gate i to all quad lanes
#define QP_B1 0x55   // [1,1,1,1] -> gate f
#define QP_B2 0xAA   // [2,2,2,2] -> gate g
#define QP_B3 0xFF   // [3,3,3,3] -> gate o
#define DPP_ROR4  0x124
#define DPP_ROR8  0x128
#define SWZ(v, pat) __int_as_float(__builtin_amdgcn_ds_swizzle(__float_as_int(v), (pat)))

__device__ __forceinline__ float hw_exp2(float x) {
    float r; asm("v_exp_f32 %0, %1" : "=v"(r) : "v"(x)); return r;
}
__device__ __forceinline__ float sigm_e(float z, float e) {
    return __builtin_amdgcn_rcpf(1.0f + hw_exp2(z * e));
}
__device__ __forceinline__ v2f pk_fma(v2f a, v2f b, v2f c) {
    return __builtin_elementwise_fma(a, b, c);   // v_pk_fma_f32
}
__device__ __forceinline__ void load_bc(const float* p, v2f* d) {
#pragma unroll
    for (int r = 0; r < 8; ++r) {                // 8x ds_read_b128 broadcast (conflict-free)
        float4 v = ((const float4*)p)[r];
        d[2*r]   = (v2f){v.x, v.y};
        d[2*r+1] = (v2f){v.z, v.w};
    }
}
// TF output path: full cross-lane sum
__device__ __forceinline__ float out_reduce(float p) {
    p += DPPF(p, DPP_ROR4);
    p += DPPF(p, DPP_ROR8);
    p += SWZ(p, 0x401F);             // xor16
    p += __shfl_xor(p, 32, 64);
    return p;
}

// 2-row (A,B) dot over 16 v2f weight regs; ACC=false starts with pk_mul
template<bool ACC>
__device__ __forceinline__ void dot2(const v2f* hv, const v2f* mA, const v2f* mB,
                                     v2f& P0, v2f& P1, v2f& P2, v2f& P3) {
    if (ACC) {
        P0 = pk_fma(hv[0], mA[0], P0); P1 = pk_fma(hv[1], mA[1], P1);
        P2 = pk_fma(hv[0], mB[0], P2); P3 = pk_fma(hv[1], mB[1], P3);
    } else {
        P0 = hv[0] * mA[0]; P1 = hv[1] * mA[1];
        P2 = hv[0] * mB[0]; P3 = hv[1] * mB[1];
    }
#pragma unroll
    for (int r = 2; r < 16; r += 2) {
        P0 = pk_fma(hv[r],   mA[r],   P0);
        P1 = pk_fma(hv[r+1], mA[r+1], P1);
        P2 = pk_fma(hv[r],   mB[r],   P2);
        P3 = pk_fma(hv[r+1], mB[r+1], P3);
    }
}

__device__ __forceinline__ void gate_hc(float zA, float zB, float es, float mm, float cc,
                                        float& cA, float& cB, float& hA, float& hB) {
    float acA = fmaf(mm, sigm_e(zA, es), cc);
    float acB = fmaf(mm, sigm_e(zB, es), cc);
    float iA = DPPF(acA, QP_B0), fA = DPPF(acA, QP_B1);
    float gA = DPPF(acA, QP_B2), oA = DPPF(acA, QP_B3);
    float iB = DPPF(acB, QP_B0), fB = DPPF(acB, QP_B1);
    float gB = DPPF(acB, QP_B2), oB = DPPF(acB, QP_B3);
    cA = fmaf(fA, cA, iA * gA);
    cB = fmaf(fB, cB, iB * gB);
    hA = oA * fmaf(2.0f, sigm_e(cA, -2.0f * LOG2E), -1.0f);
    hB = oB * fmaf(2.0f, sigm_e(cB, -2.0f * LOG2E), -1.0f);
}

// Layout (both waves): q=lane&3 (gate 0=i 1=f 2=g 3=o), ch=lane>>2 (0..15).
// Lane owns rows rowA=(q<<5)|ch and rowB=(q<<5)|(ch+16).
// TF REBALANCED (r7-verified): w0 = cell1 + Wih2·h1 partial dot (zring);
//                              w1 = cell2 gate + Whh2 dot + output.
// AR: r2-verified 2-wave structure (2 barriers/step, per-lane wl feedback on w0).
__global__ __launch_bounds__(128, 2)
void lstm_seq_kernel(const float* __restrict__ input,
                     const float* __restrict__ W_ih1, const float* __restrict__ W_hh1,
                     const float* __restrict__ b_ih1, const float* __restrict__ b_hh1,
                     const float* __restrict__ W_ih2, const float* __restrict__ W_hh2,
                     const float* __restrict__ b_ih2, const float* __restrict__ b_hh2,
                     const float* __restrict__ W_lin, const float* __restrict__ b_lin,
                     float* __restrict__ out, int T, int total)
{
    const int b    = blockIdx.x;     // one block (2 waves) per batch element
    const int tid  = threadIdx.x;
    const int w    = tid >> 6;       // wave0 = cell1 (+ih2 dot), wave1 = cell2 (+TF out)
    const int lane = tid & 63;
    const int q    = lane & 3;
    const int ch   = lane >> 2;      // 0..15
    const int rowA = (q << 5) | ch;
    const int rowB = (q << 5) | (ch + 16);
    const int zidx = (q << 4) | ch;  // 0..63; 2 lanes/bank -> conflict-free

    __shared__ __align__(16) float zring[2 * KCH * 128]; // Wih2·h1(t) row partials
    __shared__ __align__(16) float h1self[HH];           // w0 TF self-roundtrip
    __shared__ __align__(16) float h1x[HH];              // AR h1 exchange
    __shared__ __align__(16) float h2s[HH];              // w1 h2 self-roundtrip / AR feedback

    const bool  isg = (q == 2);
    const float es  = isg ? (-2.0f * LOG2E) : (-LOG2E);
    const float mm  = isg ? 2.0f : 1.0f;
    const float cc  = isg ? -1.0f : 0.0f;

    // ---- per-wave weights ----
    // w0: m1=Whh1 rows, m2=Wih2 rows (TF partial dot). w1: m1=Wih2 rows, m2=Whh2 rows.
    v2f m1A[16], m1B[16], m2A[16], m2B[16];
    float wxA = 0.f, wxB = 0.f, bA, bB, blin;
    const float wlA = W_lin[ch], wlB = W_lin[ch + 16];
    if (w == 0) {
        const v2f* pA = (const v2f*)(W_hh1 + rowA * HH);
        const v2f* pB = (const v2f*)(W_hh1 + rowB * HH);
        const v2f* qA = (const v2f*)(W_ih2 + rowA * HH);
        const v2f* qB = (const v2f*)(W_ih2 + rowB * HH);
#pragma unroll
        for (int r = 0; r < 16; ++r) { m1A[r] = pA[r]; m1B[r] = pB[r];
                                       m2A[r] = qA[r]; m2B[r] = qB[r]; }
        wxA = W_ih1[rowA]; wxB = W_ih1[rowB];
        bA  = b_ih1[rowA] + b_hh1[rowA];
        bB  = b_ih1[rowB] + b_hh1[rowB];
    } else {
        const v2f* pA = (const v2f*)(W_ih2 + rowA * HH);
        const v2f* pB = (const v2f*)(W_ih2 + rowB * HH);
        const v2f* qA = (const v2f*)(W_hh2 + rowA * HH);
        const v2f* qB = (const v2f*)(W_hh2 + rowB * HH);
#pragma unroll
        for (int r = 0; r < 16; ++r) { m1A[r] = pA[r]; m1B[r] = pB[r];
                                       m2A[r] = qA[r]; m2B[r] = qB[r]; }
        bA  = b_ih2[rowA] + b_hh2[rowA];
        bB  = b_ih2[rowB] + b_hh2[rowB];
    }
    blin = b_lin[0];

    float cA = 0.f, cB = 0.f;        // c1 (wave0) / c2 (wave1)
    // carried dots: w0: Whh1·h1(t-1); w1: Whh2·h2(t-1)
    v2f p0 = {0.f,0.f}, p1 = {0.f,0.f}, p2 = {0.f,0.f}, p3 = {0.f,0.f};

    const float* __restrict__ inp  = input + (size_t)b * T;
    float* __restrict__       outp = out   + (size_t)b * total;

    // ================= Teacher-forced phase: chunk pipeline, rebalanced ==========
    if (w == 0) {
        int t = 0;
        float xcur = inp[0];
        for (int cb = 0; t < T; ++cb) {
            float* zbuf = zring + (cb & 1) * (KCH * 128);
            int S = T - t; if (S > KCH) S = KCH;
            for (int s = 0; s < S; ++s, ++t) {
                float x = xcur;
                int tn = t + 1;
                xcur = inp[tn < T ? tn : 0];            // prefetch, off-path
                v2f tA = p0 + p1, tB = p2 + p3;
                float z1A = fmaf(x, wxA, bA + tA.x + tA.y);
                float z1B = fmaf(x, wxB, bB + tB.x + tB.y);
                float hA, hB;
                gate_hc(z1A, z1B, es, mm, cc, cA, cB, hA, hB);
                if (q == 0) { h1self[ch] = hA; h1self[ch + 16] = hB; }
                v2f hv[16]; load_bc(h1self, hv);         // same-wave round trip
                dot2<false>(hv, m1A, m1B, p0, p1, p2, p3);   // Whh1·h1(t) carry
                v2f s0, s1, s2, s3;
                dot2<false>(hv, m2A, m2B, s0, s1, s2, s3);   // Wih2·h1(t) for w1
                v2f uA = s0 + s1, uB = s2 + s3;
                float* zs = zbuf + s * 128;
                zs[zidx]      = uA.x + uA.y;             // 2 lanes/bank: conflict-free
                zs[zidx + 64] = uB.x + uB.y;
            }
            __syncthreads();          // chunk (zring half) published
        }
        __syncthreads();              // match consumer
    } else {
        __syncthreads();              // wait for chunk 0
        int t = 0;
        for (int cb = 0; t < T; ++cb) {
            const float* zbuf = zring + (cb & 1) * (KCH * 128);
            int S = T - t; if (S > KCH) S = KCH;
            for (int s = 0; s < S; ++s, ++t) {
                const float* zs = zbuf + s * 128;
                float zihA = zs[zidx], zihB = zs[zidx + 64];
                v2f tA = p0 + p1, tB = p2 + p3;
                float z2A = bA + zihA + tA.x + tA.y;     // bias + Wih2·h1 + Whh2·h2
                float z2B = bB + zihB + tB.x + tB.y;
                float hA, hB;
                gate_hc(z2A, z2B, es, mm, cc, cA, cB, hA, hB);
                if (q == 0) { h2s[ch] = hA; h2s[ch + 16] = hB; }
                v2f gv[16]; load_bc(h2s, gv);            // same-wave round trip
                dot2<false>(gv, m2A, m2B, p0, p1, p2, p3);   // Whh2·h2(t) carry
                float pr = fmaf(hA, wlA, hB * wlB);
                float ov = out_reduce(pr) + blin;
                if (lane == 0) outp[t] = ov;
            }
            __syncthreads();
        }
    }

    // ================= Autoregressive phase: r2-verified 2-wave, 2 barriers/step ==
    // w0 recomputes x(t) = Wlin·h2(t-1)+b per-lane from the h2s broadcast.
    v2f wl[16];
    if (w == 0) {                     // m2 (Wih2 copy) dead after TF -> RA reuses
        const v2f* wp = (const v2f*)W_lin;
#pragma unroll
        for (int r = 0; r < 16; ++r) wl[r] = wp[r];
    }
    for (int t = T; t < total; ++t) {
        __syncthreads();                        // BX: h2s(t-1) visible, h1x WAR safe
        if (w == 0) {
            v2f gv[16]; load_bc(h2s, gv);
            v2f oa = gv[0] * wl[0], ob = gv[1] * wl[1];
#pragma unroll
            for (int r = 2; r < 16; r += 2) { oa = pk_fma(gv[r],   wl[r],   oa);
                                              ob = pk_fma(gv[r+1], wl[r+1], ob); }
            float xo = (oa.x + oa.y) + (ob.x + ob.y) + blin;   // = out(t-1)
            if (t > T && lane == 0) outp[t - 1] = xo;          // outp[T-1] done by TF
            v2f tA = p0 + p1, tB = p2 + p3;
            float z1A = fmaf(xo, wxA, bA + tA.x + tA.y);
            float z1B = fmaf(xo, wxB, bB + tB.x + tB.y);
            float hA, hB;
            gate_hc(z1A, z1B, es, mm, cc, cA, cB, hA, hB);
            if (q == 0) { h1x[ch] = hA; h1x[ch + 16] = hB; }
        } else {
            v2f gv[16]; load_bc(h2s, gv);       // own write from prev step
            dot2<false>(gv, m2A, m2B, p0, p1, p2, p3);   // refresh Whh2·h2 carry
        }
        __syncthreads();                        // BH: h1x visible
        if (w == 0) {
            v2f hv[16]; load_bc(h1x, hv);       // next z1 carry (shadow)
            dot2<false>(hv, m1A, m1B, p0, p1, p2, p3);
        } else {
            v2f hv[16]; load_bc(h1x, hv);
            dot2<true>(hv, m1A, m1B, p0, p1, p2, p3);    // in place: p dead after z2
            v2f tA = p0 + p1, tB = p2 + p3;
            float z2A = bA + tA.x + tA.y;
            float z2B = bB + tB.x + tB.y;
            float hA, hB;
            gate_hc(z2A, z2B, es, mm, cc, cA, cB, hA, hB);
            if (q == 0) { h2s[ch] = hA; h2s[ch + 16] = hB; }
        }
    }
    // tail: final output out(total-1) = Wlin·h2(total-1)+b
    __syncthreads();
    if (w == 0) {
        v2f gv[16]; load_bc(h2s, gv);
        v2f oa = gv[0] * wl[0], ob = gv[1] * wl[1];
#pragma unroll
        for (int r = 2; r < 16; r += 2) { oa = pk_fma(gv[r],   wl[r],   oa);
                                          ob = pk_fma(gv[r+1], wl[r+1], ob); }
        if (lane == 0) outp[total - 1] = (oa.x + oa.y) + (ob.x + ob.y) + blin;
    }
}

extern "C" void kernel_launch(void* const* d_in, const int* in_sizes, int n_in,
                              void* d_out, int out_size, void* d_ws, size_t ws_size,
                              hipStream_t stream) {
    const int B = 1024;                 // fixed by the source module
    const int T = in_sizes[0] / B;      // 999
    const int total = out_size / B;     // T + future = 1999

    lstm_seq_kernel<<<dim3(B), dim3(128), 0, stream>>>(
        (const float*)d_in[0],
        (const float*)d_in[1], (const float*)d_in[2],
        (const float*)d_in[3], (const float*)d_in[4],
        (const float*)d_in[5], (const float*)d_in[6],
        (const float*)d_in[7], (const float*)d_in[8],
        (const float*)d_in[9], (const float*)d_in[10],
        (float*)d_out, T, total);
}

// Round 12
// 1151.313 us; speedup vs baseline: 1.2313x; 1.0191x over previous
//
#include <hip/hip_runtime.h>

#define HH 32
#define LOG2E 1.44269504088896340736f
#define KCH 16   // TF pipeline chunk length (steps per ring half)

typedef float v2f __attribute__((ext_vector_type(2)));

// DPP: quad_perm broadcasts (gate q = lane&3) and row rotates (16-lane rows)
#define DPPF(v, ctrl) \
    __int_as_float(__builtin_amdgcn_update_dpp(0, __float_as_int(v), (ctrl), 0xF, 0xF, true))
#define QP_B0 0x00   // [0,0,0,0] -> gate i to all quad lanes
#define QP_B1 0x55   // [1,1,1,1] -> gate f
#define QP_B2 0xAA   // [2,2,2,2] -> gate g
#define QP_B3 0xFF   // [3,3,3,3] -> gate o
#define DPP_ROR4  0x124
#define DPP_ROR8  0x128
#define SWZ(v, pat) __int_as_float(__builtin_amdgcn_ds_swizzle(__float_as_int(v), (pat)))

__device__ __forceinline__ float hw_exp2(float x) {
    float r; asm("v_exp_f32 %0, %1" : "=v"(r) : "v"(x)); return r;
}
__device__ __forceinline__ float sigm_e(float z, float e) {
    return __builtin_amdgcn_rcpf(1.0f + hw_exp2(z * e));
}
__device__ __forceinline__ v2f pk_fma(v2f a, v2f b, v2f c) {
    return __builtin_elementwise_fma(a, b, c);   // v_pk_fma_f32
}
__device__ __forceinline__ void load_bc(const float* p, v2f* d) {
#pragma unroll
    for (int r = 0; r < 8; ++r) {                // 8x ds_read_b128 broadcast (conflict-free)
        float4 v = ((const float4*)p)[r];
        d[2*r]   = (v2f){v.x, v.y};
        d[2*r+1] = (v2f){v.z, v.w};
    }
}
// TF output path: full cross-lane sum
__device__ __forceinline__ float out_reduce(float p) {
    p += DPPF(p, DPP_ROR4);
    p += DPPF(p, DPP_ROR8);
    p += SWZ(p, 0x401F);             // xor16
    p += __shfl_xor(p, 32, 64);
    return p;
}

// 2-row (A,B) dot over 16 v2f weight regs; ACC=false starts with pk_mul
template<bool ACC>
__device__ __forceinline__ void dot2(const v2f* hv, const v2f* mA, const v2f* mB,
                                     v2f& P0, v2f& P1, v2f& P2, v2f& P3) {
    if (ACC) {
        P0 = pk_fma(hv[0], mA[0], P0); P1 = pk_fma(hv[1], mA[1], P1);
        P2 = pk_fma(hv[0], mB[0], P2); P3 = pk_fma(hv[1], mB[1], P3);
    } else {
        P0 = hv[0] * mA[0]; P1 = hv[1] * mA[1];
        P2 = hv[0] * mB[0]; P3 = hv[1] * mB[1];
    }
#pragma unroll
    for (int r = 2; r < 16; r += 2) {
        P0 = pk_fma(hv[r],   mA[r],   P0);
        P1 = pk_fma(hv[r+1], mA[r+1], P1);
        P2 = pk_fma(hv[r],   mB[r],   P2);
        P3 = pk_fma(hv[r+1], mB[r+1], P3);
    }
}

__device__ __forceinline__ void gate_hc(float zA, float zB, float es, float mm, float cc,
                                        float& cA, float& cB, float& hA, float& hB) {
    float acA = fmaf(mm, sigm_e(zA, es), cc);
    float acB = fmaf(mm, sigm_e(zB, es), cc);
    float iA = DPPF(acA, QP_B0), fA = DPPF(acA, QP_B1);
    float gA = DPPF(acA, QP_B2), oA = DPPF(acA, QP_B3);
    float iB = DPPF(acB, QP_B0), fB = DPPF(acB, QP_B1);
    float gB = DPPF(acB, QP_B2), oB = DPPF(acB, QP_B3);
    cA = fmaf(fA, cA, iA * gA);
    cB = fmaf(fB, cB, iB * gB);
    hA = oA * fmaf(2.0f, sigm_e(cA, -2.0f * LOG2E), -1.0f);
    hB = oB * fmaf(2.0f, sigm_e(cB, -2.0f * LOG2E), -1.0f);
}

// Layout (both waves): q=lane&3 (gate 0=i 1=f 2=g 3=o), ch=lane>>2 (0..15).
// Lane owns rows rowA=(q<<5)|ch and rowB=(q<<5)|(ch+16).
// TF REBALANCED (r7-verified best, 1156us): w0 = cell1 + Wih2·h1 partial dot (zring);
//                                           w1 = cell2 gate + Whh2 dot + output.
// AR: r2-verified 2-wave structure (2 barriers/step, per-lane wl feedback on w0).
__global__ __launch_bounds__(128, 2)
void lstm_seq_kernel(const float* __restrict__ input,
                     const float* __restrict__ W_ih1, const float* __restrict__ W_hh1,
                     const float* __restrict__ b_ih1, const float* __restrict__ b_hh1,
                     const float* __restrict__ W_ih2, const float* __restrict__ W_hh2,
                     const float* __restrict__ b_ih2, const float* __restrict__ b_hh2,
                     const float* __restrict__ W_lin, const float* __restrict__ b_lin,
                     float* __restrict__ out, int T, int total)
{
    const int b    = blockIdx.x;     // one block (2 waves) per batch element
    const int tid  = threadIdx.x;
    const int w    = tid >> 6;       // wave0 = cell1 (+ih2 dot), wave1 = cell2 (+TF out)
    const int lane = tid & 63;
    const int q    = lane & 3;
    const int ch   = lane >> 2;      // 0..15
    const int rowA = (q << 5) | ch;
    const int rowB = (q << 5) | (ch + 16);
    const int zidx = (q << 4) | ch;  // 0..63; 2 lanes/bank -> conflict-free

    __shared__ __align__(16) float zring[2 * KCH * 128]; // Wih2·h1(t) row partials
    __shared__ __align__(16) float h1self[HH];           // w0 TF self-roundtrip
    __shared__ __align__(16) float h1x[HH];              // AR h1 exchange
    __shared__ __align__(16) float h2s[HH];              // w1 h2 self-roundtrip / AR feedback

    const bool  isg = (q == 2);
    const float es  = isg ? (-2.0f * LOG2E) : (-LOG2E);
    const float mm  = isg ? 2.0f : 1.0f;
    const float cc  = isg ? -1.0f : 0.0f;

    // ---- per-wave weights ----
    // w0: m1=Whh1 rows, m2=Wih2 rows (TF partial dot). w1: m1=Wih2 rows, m2=Whh2 rows.
    v2f m1A[16], m1B[16], m2A[16], m2B[16];
    float wxA = 0.f, wxB = 0.f, bA, bB, blin;
    const float wlA = W_lin[ch], wlB = W_lin[ch + 16];
    if (w == 0) {
        const v2f* pA = (const v2f*)(W_hh1 + rowA * HH);
        const v2f* pB = (const v2f*)(W_hh1 + rowB * HH);
        const v2f* qA = (const v2f*)(W_ih2 + rowA * HH);
        const v2f* qB = (const v2f*)(W_ih2 + rowB * HH);
#pragma unroll
        for (int r = 0; r < 16; ++r) { m1A[r] = pA[r]; m1B[r] = pB[r];
                                       m2A[r] = qA[r]; m2B[r] = qB[r]; }
        wxA = W_ih1[rowA]; wxB = W_ih1[rowB];
        bA  = b_ih1[rowA] + b_hh1[rowA];
        bB  = b_ih1[rowB] + b_hh1[rowB];
    } else {
        const v2f* pA = (const v2f*)(W_ih2 + rowA * HH);
        const v2f* pB = (const v2f*)(W_ih2 + rowB * HH);
        const v2f* qA = (const v2f*)(W_hh2 + rowA * HH);
        const v2f* qB = (const v2f*)(W_hh2 + rowB * HH);
#pragma unroll
        for (int r = 0; r < 16; ++r) { m1A[r] = pA[r]; m1B[r] = pB[r];
                                       m2A[r] = qA[r]; m2B[r] = qB[r]; }
        bA  = b_ih2[rowA] + b_hh2[rowA];
        bB  = b_ih2[rowB] + b_hh2[rowB];
    }
    blin = b_lin[0];

    float cA = 0.f, cB = 0.f;        // c1 (wave0) / c2 (wave1)
    // carried dots: w0: Whh1·h1(t-1); w1: Whh2·h2(t-1)
    v2f p0 = {0.f,0.f}, p1 = {0.f,0.f}, p2 = {0.f,0.f}, p3 = {0.f,0.f};

    const float* __restrict__ inp  = input + (size_t)b * T;
    float* __restrict__       outp = out   + (size_t)b * total;

    // ================= Teacher-forced phase: chunk pipeline, rebalanced ==========
    if (w == 0) {
        int t = 0;
        float xcur = inp[0];
        for (int cb = 0; t < T; ++cb) {
            float* zbuf = zring + (cb & 1) * (KCH * 128);
            int S = T - t; if (S > KCH) S = KCH;
            for (int s = 0; s < S; ++s, ++t) {
                float x = xcur;
                int tn = t + 1;
                xcur = inp[tn < T ? tn : 0];            // prefetch, off-path
                v2f tA = p0 + p1, tB = p2 + p3;
                float z1A = fmaf(x, wxA, bA + tA.x + tA.y);
                float z1B = fmaf(x, wxB, bB + tB.x + tB.y);
                float hA, hB;
                gate_hc(z1A, z1B, es, mm, cc, cA, cB, hA, hB);
                if (q == 0) { h1self[ch] = hA; h1self[ch + 16] = hB; }
                v2f hv[16]; load_bc(h1self, hv);         // same-wave round trip
                dot2<false>(hv, m1A, m1B, p0, p1, p2, p3);   // Whh1·h1(t) carry
                v2f s0, s1, s2, s3;
                dot2<false>(hv, m2A, m2B, s0, s1, s2, s3);   // Wih2·h1(t) for w1
                v2f uA = s0 + s1, uB = s2 + s3;
                float* zs = zbuf + s * 128;
                zs[zidx]      = uA.x + uA.y;             // 2 lanes/bank: conflict-free
                zs[zidx + 64] = uB.x + uB.y;
            }
            __syncthreads();          // chunk (zring half) published
        }
        __syncthreads();              // match consumer
    } else {
        __syncthreads();              // wait for chunk 0
        int t = 0;
        for (int cb = 0; t < T; ++cb) {
            const float* zbuf = zring + (cb & 1) * (KCH * 128);
            int S = T - t; if (S > KCH) S = KCH;
            for (int s = 0; s < S; ++s, ++t) {
                const float* zs = zbuf + s * 128;
                float zihA = zs[zidx], zihB = zs[zidx + 64];
                v2f tA = p0 + p1, tB = p2 + p3;
                float z2A = bA + zihA + tA.x + tA.y;     // bias + Wih2·h1 + Whh2·h2
                float z2B = bB + zihB + tB.x + tB.y;
                float hA, hB;
                gate_hc(z2A, z2B, es, mm, cc, cA, cB, hA, hB);
                if (q == 0) { h2s[ch] = hA; h2s[ch + 16] = hB; }
                v2f gv[16]; load_bc(h2s, gv);            // same-wave round trip
                dot2<false>(gv, m2A, m2B, p0, p1, p2, p3);   // Whh2·h2(t) carry
                float pr = fmaf(hA, wlA, hB * wlB);
                float ov = out_reduce(pr) + blin;
                if (lane == 0) outp[t] = ov;
            }
            __syncthreads();
        }
    }

    // ================= Autoregressive phase: r2-verified 2-wave, 2 barriers/step ==
    // w0 recomputes x(t) = Wlin·h2(t-1)+b per-lane from the h2s broadcast.
    v2f wl[16];
    if (w == 0) {                     // m2 (Wih2 copy) dead after TF -> RA reuses
        const v2f* wp = (const v2f*)W_lin;
#pragma unroll
        for (int r = 0; r < 16; ++r) wl[r] = wp[r];
    }
    for (int t = T; t < total; ++t) {
        __syncthreads();                        // BX: h2s(t-1) visible, h1x WAR safe
        if (w == 0) {
            v2f gv[16]; load_bc(h2s, gv);
            v2f oa = gv[0] * wl[0], ob = gv[1] * wl[1];
#pragma unroll
            for (int r = 2; r < 16; r += 2) { oa = pk_fma(gv[r],   wl[r],   oa);
                                              ob = pk_fma(gv[r+1], wl[r+1], ob); }
            float xo = (oa.x + oa.y) + (ob.x + ob.y) + blin;   // = out(t-1)
            if (t > T && lane == 0) outp[t - 1] = xo;          // outp[T-1] done by TF
            v2f tA = p0 + p1, tB = p2 + p3;
            float z1A = fmaf(xo, wxA, bA + tA.x + tA.y);
            float z1B = fmaf(xo, wxB, bB + tB.x + tB.y);
            float hA, hB;
            gate_hc(z1A, z1B, es, mm, cc, cA, cB, hA, hB);
            if (q == 0) { h1x[ch] = hA; h1x[ch + 16] = hB; }
        } else {
            v2f gv[16]; load_bc(h2s, gv);       // own write from prev step
            dot2<false>(gv, m2A, m2B, p0, p1, p2, p3);   // refresh Whh2·h2 carry
        }
        __syncthreads();                        // BH: h1x visible
        if (w == 0) {
            v2f hv[16]; load_bc(h1x, hv);       // next z1 carry (shadow)
            dot2<false>(hv, m1A, m1B, p0, p1, p2, p3);
        } else {
            v2f hv[16]; load_bc(h1x, hv);
            dot2<true>(hv, m1A, m1B, p0, p1, p2, p3);    // in place: p dead after z2
            v2f tA = p0 + p1, tB = p2 + p3;
            float z2A = bA + tA.x + tA.y;
            float z2B = bB + tB.x + tB.y;
            float hA, hB;
            gate_hc(z2A, z2B, es, mm, cc, cA, cB, hA, hB);
            if (q == 0) { h2s[ch] = hA; h2s[ch + 16] = hB; }
        }
    }
    // tail: final output out(total-1) = Wlin·h2(total-1)+b
    __syncthreads();
    if (w == 0) {
        v2f gv[16]; load_bc(h2s, gv);
        v2f oa = gv[0] * wl[0], ob = gv[1] * wl[1];
#pragma unroll
        for (int r = 2; r < 16; r += 2) { oa = pk_fma(gv[r],   wl[r],   oa);
                                          ob = pk_fma(gv[r+1], wl[r+1], ob); }
        if (lane == 0) outp[total - 1] = (oa.x + oa.y) + (ob.x + ob.y) + blin;
    }
}

extern "C" void kernel_launch(void* const* d_in, const int* in_sizes, int n_in,
                              void* d_out, int out_size, void* d_ws, size_t ws_size,
                              hipStream_t stream) {
    const int B = 1024;                 // fixed by the source module
    const int T = in_sizes[0] / B;      // 999
    const int total = out_size / B;     // T + future = 1999

    lstm_seq_kernel<<<dim3(B), dim3(128), 0, stream>>>(
        (const float*)d_in[0],
        (const float*)d_in[1], (const float*)d_in[2],
        (const float*)d_in[3], (const float*)d_in[4],
        (const float*)d_in[5], (const float*)d_in[6],
        (const float*)d_in[7], (const float*)d_in[8],
        (const float*)d_in[9], (const float*)d_in[10],
        (float*)d_out, T, total);
}